// Round 8
// baseline (347.467 us; speedup 1.0000x reference)
//
#include <hip/hip_runtime.h>
#include <math.h>

constexpr int NB = 8;
constexpr int NC = 256;
constexpr int NCR = 64;
constexpr int NH = 160;
constexpr int NW = 160;
constexpr int NHW = NH * NW;           // 25600
constexpr float KEPS = 1e-4f;

constexpr int TW = 32;                 // tile width (k_logits)
constexpr int TH = 8;                  // tile height (k_logits)

// K0: transpose rw[d][c] -> rwT[c][d]; block 0 also zeroes pooledsum
__global__ __launch_bounds__(256) void k_tr(const float* __restrict__ rw,
                                            float* __restrict__ rwT,
                                            float* __restrict__ pooledsum) {
    const int i = blockIdx.x * 256 + threadIdx.x;    // over 16384
    const int d = i >> 8, c = i & 255;
    rwT[c * NCR + d] = rw[i];
    if (blockIdx.x == 0) {
        pooledsum[threadIdx.x] = 0.f;
        pooledsum[256 + threadIdx.x] = 0.f;
    }
}

#define FMA4(A, X, W) \
    A.x = fmaf((X).x, (W), A.x); A.y = fmaf((X).y, (W), A.y); \
    A.z = fmaf((X).z, (W), A.z); A.w = fmaf((X).w, (W), A.w)

// K1: y[b,d,p] = sum_c x[b,c,p] * rwT[c][d] for a 32-d half; pooled sums too.
// Thread = 8 px (2x float4) x 8 d -> 16 NAMED float4 accs (64 VGPR, no spill).
// Block = 4 waves x 8 d = 32 d for 512 px; blockIdx.z = d-half. LDS = 32 KB
// half-weights -> 4 blocks/CU; launch_bounds(256,4) -> 4 waves/SIMD TLP.
__global__ __launch_bounds__(256, 4) void k_reduce(const float* __restrict__ x,
                                                   const float* __restrict__ rwT,
                                                   float* __restrict__ y,
                                                   float* __restrict__ pooledsum) {
    __shared__ float wlds[NC * 32];                  // 32 KB: [c][32 d of half]
    const int t = threadIdx.x;
    const int lane = t & 63;
    const int wv = t >> 6;                           // wave id 0..3
    const int half = blockIdx.z;                     // d base = half*32
    const int b = blockIdx.y;
    const int p0 = blockIdx.x * 512 + lane * 4;      // px group0; group1 = +256

    {   // stage half-weights: 2048 float4, 8 per thread
        const float4* src = reinterpret_cast<const float4*>(rwT);
        float4* dst = reinterpret_cast<float4*>(wlds);
#pragma unroll
        for (int i = 0; i < 8; ++i) {
            const int idx = i * 256 + t;             // 0..2047 = c*8 + j
            const int c = idx >> 3, j = idx & 7;
            dst[idx] = src[c * 16 + half * 8 + j];
        }
    }
    __syncthreads();

    const float* xb = x + (size_t)b * NC * NHW + p0;

    float4 A0{0,0,0,0}, A1{0,0,0,0}, A2{0,0,0,0}, A3{0,0,0,0};
    float4 A4{0,0,0,0}, A5{0,0,0,0}, A6{0,0,0,0}, A7{0,0,0,0};
    float4 B0{0,0,0,0}, B1{0,0,0,0}, B2{0,0,0,0}, B3{0,0,0,0};
    float4 B4{0,0,0,0}, B5{0,0,0,0}, B6{0,0,0,0}, B7{0,0,0,0};

    float4 xc0 = *reinterpret_cast<const float4*>(xb);
    float4 xc1 = *reinterpret_cast<const float4*>(xb + 256);

    for (int c = 0; c < NC; ++c) {
        float4 xn0, xn1;
        if (c + 1 < NC) {
            xn0 = *reinterpret_cast<const float4*>(xb + (size_t)(c + 1) * NHW);
            xn1 = *reinterpret_cast<const float4*>(xb + (size_t)(c + 1) * NHW + 256);
        }
        const float4* wr = reinterpret_cast<const float4*>(wlds + c * 32 + wv * 8);
        const float4 w0 = wr[0], w1 = wr[1];
        FMA4(A0, xc0, w0.x); FMA4(A1, xc0, w0.y); FMA4(A2, xc0, w0.z); FMA4(A3, xc0, w0.w);
        FMA4(A4, xc0, w1.x); FMA4(A5, xc0, w1.y); FMA4(A6, xc0, w1.z); FMA4(A7, xc0, w1.w);
        FMA4(B0, xc1, w0.x); FMA4(B1, xc1, w0.y); FMA4(B2, xc1, w0.z); FMA4(B3, xc1, w0.w);
        FMA4(B4, xc1, w1.x); FMA4(B5, xc1, w1.y); FMA4(B6, xc1, w1.z); FMA4(B7, xc1, w1.w);
        if (c + 1 < NC) { xc0 = xn0; xc1 = xn1; }
    }

    const int dbase = half * 32 + wv * 8;
    float* yb = y + ((size_t)b * NCR + dbase) * NHW + p0;
#define YST(K, A, B) \
    *reinterpret_cast<float4*>(yb + (size_t)(K) * NHW) = A; \
    *reinterpret_cast<float4*>(yb + (size_t)(K) * NHW + 256) = B;
    YST(0, A0, B0); YST(1, A1, B1); YST(2, A2, B2); YST(3, A3, B3);
    YST(4, A4, B4); YST(5, A5, B5); YST(6, A6, B6); YST(7, A7, B7);
#undef YST

    float* ps = pooledsum + b * NCR + dbase;
#define PRED(K, A, B) { \
    float s_ = A.x + A.y + A.z + A.w + B.x + B.y + B.z + B.w; \
    _Pragma("unroll") \
    for (int o_ = 32; o_ > 0; o_ >>= 1) s_ += __shfl_down(s_, o_, 64); \
    if (lane == 0) atomicAdd(&ps[K], s_); }
    PRED(0, A0, B0); PRED(1, A1, B1); PRED(2, A2, B2); PRED(3, A3, B3);
    PRED(4, A4, B4); PRED(5, A5, B5); PRED(6, A6, B6); PRED(7, A7, B7);
#undef PRED
}

// K2: gamma[b,d] = sigmoid(relu(mean@w1^T+b1)@w2^T+b2); pooledsum -> mean
__global__ __launch_bounds__(512) void k_gate(const float* __restrict__ pooledsum,
                                              const float* __restrict__ w1,
                                              const float* __restrict__ b1,
                                              const float* __restrict__ w2,
                                              const float* __restrict__ b2,
                                              float* __restrict__ gamma) {
    __shared__ float hsh[NB][16];
    const int t = threadIdx.x;
    constexpr float inv = 1.f / (float)NHW;
    if (t < NB * 16) {
        const int b = t / 16, j = t % 16;
        float s = b1[j];
        for (int d = 0; d < NCR; ++d)
            s = fmaf(pooledsum[b * NCR + d] * inv, w1[j * NCR + d], s);
        hsh[b][j] = fmaxf(s, 0.f);
    }
    __syncthreads();
    const int b = t / NCR, d = t % NCR;
    float s = b2[d];
#pragma unroll
    for (int j = 0; j < 16; ++j) s = fmaf(hsh[b][j], w2[d * 16 + j], s);
    gamma[t] = 1.f / (1.f + expf(-s));
}

// K3a: per (b, 32x8 tile): stencil on y -> kappa -> logits -> m = 1+sigmoid
__global__ __launch_bounds__(256) void k_logits(const float* __restrict__ y,
                                                const float* __restrict__ gamma,
                                                const float* __restrict__ fw,
                                                float* __restrict__ m) {
    __shared__ float tile[TH + 2][TW + 2];           // 10 x 34
    __shared__ float coef[NCR];

    const int b = blockIdx.z;
    const int w0 = blockIdx.x * TW, h0 = blockIdx.y * TH;
    const int t = threadIdx.x;
    const int tx = t % TW, ty = t / TW;

    if (t < NCR) coef[t] = fw[t] + gamma[b * NCR + t] * fw[NCR + t];
    __syncthreads();

    const float* yb = y + (size_t)b * NCR * NHW;
    float logit = 0.f;

    for (int c = 0; c < NCR; ++c) {
        const float* yc = yb + (size_t)c * NHW;
        for (int i = t; i < (TH + 2) * (TW + 2); i += 256) {
            const int iy = i / (TW + 2), ix = i % (TW + 2);
            const int gh = h0 + iy - 1, gw = w0 + ix - 1;
            float v = 0.f;
            if (gh >= 0 && gh < NH && gw >= 0 && gw < NW) v = yc[gh * NW + gw];
            tile[iy][ix] = v;
        }
        __syncthreads();

        const float a00 = tile[ty][tx],     a01 = tile[ty][tx + 1],     a02 = tile[ty][tx + 2];
        const float a10 = tile[ty + 1][tx], a11 = tile[ty + 1][tx + 1], a12 = tile[ty + 1][tx + 2];
        const float a20 = tile[ty + 2][tx], a21 = tile[ty + 2][tx + 1], a22 = tile[ty + 2][tx + 2];

        const float mu = (a00 + a01 + a02 + a10 + a11 + a12 + a20 + a21 + a22) * (1.f / 9.f);
        const float gx = (a00 - a02 + 2.f * (a10 - a12) + a20 - a22) * 0.125f;
        const float gy = (a00 + 2.f * a01 + a02 - a20 - 2.f * a21 - a22) * 0.125f;
        const float kappa = 1.f - fabsf(a11 - mu) / (fabsf(gx) + fabsf(gy) + KEPS);
        logit = fmaf(kappa, coef[c], logit);
        __syncthreads();
    }

    const float a = 1.f / (1.f + expf(-logit));
    m[(size_t)b * NHW + (h0 + ty) * NW + (w0 + tx)] = 1.f + a;
}

// K3b: pure stream out = x * m. Block: 256 thr over 1024 px; 4 channels each.
__global__ __launch_bounds__(256) void k_mul(const float* __restrict__ x,
                                             const float* __restrict__ m,
                                             float* __restrict__ out) {
    const int b = blockIdx.z;
    const int c0 = blockIdx.y * 4;
    const int p = blockIdx.x * 1024 + threadIdx.x * 4;

    const float4 mv = *reinterpret_cast<const float4*>(m + (size_t)b * NHW + p);
    const size_t base = (size_t)b * NC * NHW + (size_t)c0 * NHW + p;
    const float* xp = x + base;
    float* op = out + base;

#pragma unroll
    for (int cc = 0; cc < 4; ++cc) {
        const float4 v = *reinterpret_cast<const float4*>(xp + (size_t)cc * NHW);
        float4 r;
        r.x = v.x * mv.x; r.y = v.y * mv.y; r.z = v.z * mv.z; r.w = v.w * mv.w;
        *reinterpret_cast<float4*>(op + (size_t)cc * NHW) = r;
    }
}

extern "C" void kernel_launch(void* const* d_in, const int* in_sizes, int n_in,
                              void* d_out, int out_size, void* d_ws, size_t ws_size,
                              hipStream_t stream) {
    const float* x  = (const float*)d_in[0];
    const float* rw = (const float*)d_in[1];
    const float* w1 = (const float*)d_in[2];
    const float* b1 = (const float*)d_in[3];
    const float* w2 = (const float*)d_in[4];
    const float* b2 = (const float*)d_in[5];
    const float* fw = (const float*)d_in[6];
    float* out = (float*)d_out;

    float* y      = (float*)d_ws;                       // 13,107,200 floats
    float* pooled = y + (size_t)NB * NCR * NHW;         // 512 floats (sums)
    float* gamma  = pooled + NB * NCR;                  // 512 floats
    float* rwT    = gamma + NB * NCR;                   // 16384 floats
    float* m      = rwT + NC * NCR;                     // 204800 floats

    k_tr<<<dim3(64), 256, 0, stream>>>(rw, rwT, pooled);
    k_reduce<<<dim3(NHW / 512, NB, 2), 256, 0, stream>>>(x, rwT, y, pooled);
    k_gate<<<dim3(1), 512, 0, stream>>>(pooled, w1, b1, w2, b2, gamma);
    k_logits<<<dim3(NW / TW, NH / TH, NB), 256, 0, stream>>>(y, gamma, fw, m);
    k_mul<<<dim3(NHW / 1024, NC / 4, NB), 256, 0, stream>>>(x, m, out);
}